// Round 1
// baseline (2766.326 us; speedup 1.0000x reference)
//
#include <hip/hip_runtime.h>
#include <stdint.h>

#define DM 1024
#define NH 16
#define DH 64
#define SQ 1024
#define NB 4
#define FFD 4096
#define MAXK 1664
#define ROWS 4096
#define L2E 1.4426950408889634f

typedef __attribute__((ext_vector_type(8))) short short8;
typedef __attribute__((ext_vector_type(4))) float f32x4;

static __device__ __forceinline__ unsigned short f2bf(float f) {
    unsigned u = __float_as_uint(f);
    return (unsigned short)((u + 0x7fffu + ((u >> 16) & 1u)) >> 16);
}
static __device__ __forceinline__ float bf2f(unsigned short s) {
    return __uint_as_float(((unsigned)s) << 16);
}

// ---------------- embedding lookup: x fp32 (d_out) + xb bf16 ----------------
__global__ __launch_bounds__(256) void k_embed(const int* __restrict__ seq,
                                               const float* __restrict__ emb,
                                               float* __restrict__ x,
                                               unsigned short* __restrict__ xb) {
    const int row = blockIdx.x, t = threadIdx.x;
    const int tok = seq[row];
    const float4 v = *(const float4*)(emb + (long)tok * DM + t * 4);
    *(float4*)(x + (long)row * DM + t * 4) = v;
    ushort4 o; o.x = f2bf(v.x); o.y = f2bf(v.y); o.z = f2bf(v.z); o.w = f2bf(v.w);
    *(ushort4*)(xb + (long)row * DM + t * 4) = o;
}

// ------------- r_emb[:, :, -SQ:, :] -> bf16 [L][H][SQ][DH] ------------------
__global__ __launch_bounds__(256) void k_reb(const float* __restrict__ re,
                                             unsigned short* __restrict__ reb) {
    const long e = ((long)blockIdx.x * 256 + threadIdx.x) * 4;
    const int d = (int)(e & 63);
    const long rem = e >> 6;
    const int j = (int)(rem & 1023);
    const long lh = rem >> 10;
    const float4 v = *(const float4*)(re + (lh * MAXK + 640 + j) * DH + d);
    ushort4 o; o.x = f2bf(v.x); o.y = f2bf(v.y); o.z = f2bf(v.z); o.w = f2bf(v.w);
    *(ushort4*)(reb + e) = o;
}

// -------- LayerNorm in place on x (fp32), also writes xb (bf16) -------------
__global__ __launch_bounds__(256) void k_ln(float* __restrict__ x,
                                            unsigned short* __restrict__ xb,
                                            const float* __restrict__ gw,
                                            const float* __restrict__ bw) {
    const int row = blockIdx.x, t = threadIdx.x;
    float4 v = *(const float4*)(x + (long)row * DM + t * 4);
    float s = v.x + v.y + v.z + v.w;
    float sq = v.x * v.x + v.y * v.y + v.z * v.z + v.w * v.w;
#pragma unroll
    for (int mk = 1; mk < 64; mk <<= 1) { s += __shfl_xor(s, mk); sq += __shfl_xor(sq, mk); }
    __shared__ float red[8];
    if ((t & 63) == 0) { red[(t >> 6) * 2] = s; red[(t >> 6) * 2 + 1] = sq; }
    __syncthreads();
    const float ts = red[0] + red[2] + red[4] + red[6];
    const float tq = red[1] + red[3] + red[5] + red[7];
    const float mu = ts * (1.f / DM);
    const float rstd = rsqrtf(tq * (1.f / DM) - mu * mu + 1e-5f);
    const float4 g4 = *(const float4*)(gw + t * 4);
    const float4 b4 = *(const float4*)(bw + t * 4);
    float4 o;
    o.x = (v.x - mu) * rstd * g4.x + b4.x;
    o.y = (v.y - mu) * rstd * g4.y + b4.y;
    o.z = (v.z - mu) * rstd * g4.z + b4.z;
    o.w = (v.w - mu) * rstd * g4.w + b4.w;
    *(float4*)(x + (long)row * DM + t * 4) = o;
    ushort4 ob; ob.x = f2bf(o.x); ob.y = f2bf(o.y); ob.z = f2bf(o.z); ob.w = f2bf(o.w);
    *(ushort4*)(xb + (long)row * DM + t * 4) = ob;
}

// ---------------------------------------------------------------------------
// GEMM: C[M,N] = A(bf16,[M,K] rm) * B(fp32 weights,[N,K] rm)^T
// MT: m-frags per wave (2 -> BM=64, 4 -> BM=128), BN=128 fixed, BK=32.
// EPI 0: z selects {q,k,v} dest; q/k -> [B,H,S,dh] bf16, v -> [B,H,dh,S] bf16
// EPI 1: xres[m*DM+n] += acc + bias   (fp32 residual accumulate)
// EPI 2: d0[m*N+n] = bf16(gelu(acc + bias))   (exact erf gelu)
// ---------------------------------------------------------------------------
template <int MT, int EPI>
__global__ __launch_bounds__(256) void k_gemm(
    const unsigned short* __restrict__ A,
    const float* __restrict__ B0, const float* __restrict__ B1, const float* __restrict__ B2,
    const int K, const int N,
    float* __restrict__ xres, const float* __restrict__ bias,
    unsigned short* __restrict__ d0, unsigned short* __restrict__ d1,
    unsigned short* __restrict__ d2) {
    constexpr int BMv = MT * 32;
    __shared__ unsigned short As[BMv * 40];
    __shared__ unsigned short Bs[128 * 40];
    const int t = threadIdx.x;
    const int w = t >> 6, l = t & 63, g = l >> 4, c = l & 15;
    const int z = blockIdx.z;
    const float* Bw = (z == 0) ? B0 : ((z == 1) ? B1 : B2);
    const long m0 = (long)blockIdx.y * BMv, n0 = (long)blockIdx.x * 128;
    const int arow = (MT == 4) ? (t >> 1) : (t >> 2);
    const int aseg = (MT == 4) ? ((t & 1) * 16) : ((t & 3) * 8);
    const int brow = t >> 1, bseg = (t & 1) * 16;
    const unsigned short* asrc = A + (m0 + arow) * K + aseg;
    const float* bsrc = Bw + (n0 + brow) * K + bseg;
    f32x4 acc[MT][4];
#pragma unroll
    for (int i = 0; i < MT; i++)
#pragma unroll
        for (int j = 0; j < 4; j++) acc[i][j] = (f32x4){0.f, 0.f, 0.f, 0.f};
    const int wr = (w >> 1) * (MT * 16), wc = (w & 1) * 64;

    for (int kt = 0; kt < K; kt += 32) {
        uint4 a0, a1;
        a0 = *(const uint4*)(asrc + kt);
        if constexpr (MT == 4) a1 = *(const uint4*)(asrc + kt + 8);
        float4 f0 = *(const float4*)(bsrc + kt);
        float4 f1 = *(const float4*)(bsrc + kt + 4);
        float4 f2 = *(const float4*)(bsrc + kt + 8);
        float4 f3 = *(const float4*)(bsrc + kt + 12);
        *(uint4*)&As[arow * 40 + aseg] = a0;
        if constexpr (MT == 4) *(uint4*)&As[arow * 40 + aseg + 8] = a1;
        ushort4 u0, u1, u2, u3;
        u0.x = f2bf(f0.x); u0.y = f2bf(f0.y); u0.z = f2bf(f0.z); u0.w = f2bf(f0.w);
        u1.x = f2bf(f1.x); u1.y = f2bf(f1.y); u1.z = f2bf(f1.z); u1.w = f2bf(f1.w);
        u2.x = f2bf(f2.x); u2.y = f2bf(f2.y); u2.z = f2bf(f2.z); u2.w = f2bf(f2.w);
        u3.x = f2bf(f3.x); u3.y = f2bf(f3.y); u3.z = f2bf(f3.z); u3.w = f2bf(f3.w);
        *(ushort4*)&Bs[brow * 40 + bseg] = u0;
        *(ushort4*)&Bs[brow * 40 + bseg + 4] = u1;
        *(ushort4*)&Bs[brow * 40 + bseg + 8] = u2;
        *(ushort4*)&Bs[brow * 40 + bseg + 12] = u3;
        __syncthreads();
        short8 aF[MT], bF[4];
#pragma unroll
        for (int i = 0; i < MT; i++) aF[i] = *(const short8*)&As[(wr + i * 16 + c) * 40 + g * 8];
#pragma unroll
        for (int j = 0; j < 4; j++) bF[j] = *(const short8*)&Bs[(wc + j * 16 + c) * 40 + g * 8];
#pragma unroll
        for (int i = 0; i < MT; i++)
#pragma unroll
            for (int j = 0; j < 4; j++)
                acc[i][j] = __builtin_amdgcn_mfma_f32_16x16x32_bf16(aF[i], bF[j], acc[i][j], 0, 0, 0);
        __syncthreads();
    }

#pragma unroll
    for (int i = 0; i < MT; i++) {
#pragma unroll
        for (int j = 0; j < 4; j++) {
            const long ncol = n0 + wc + j * 16 + c;
            float bval = 0.f;
            if (EPI != 0) bval = (bias != nullptr) ? bias[ncol] : 0.f;
#pragma unroll
            for (int r = 0; r < 4; r++) {
                const long mrow = m0 + wr + i * 16 + g * 4 + r;
                const float vv = acc[i][j][r];
                if (EPI == 0) {
                    const long bb = mrow >> 10, ss = mrow & 1023, hh = ncol >> 6, dd = ncol & 63;
                    if (z == 0)      d0[((bb * NH + hh) * SQ + ss) * DH + dd] = f2bf(vv);
                    else if (z == 1) d1[((bb * NH + hh) * SQ + ss) * DH + dd] = f2bf(vv);
                    else             d2[((bb * NH + hh) * DH + dd) * SQ + ss] = f2bf(vv);
                } else if (EPI == 1) {
                    xres[mrow * DM + ncol] += vv + bval;
                } else {
                    const float xg = vv + bval;
                    d0[mrow * (long)N + ncol] = f2bf(0.5f * xg * (1.f + erff(xg * 0.70710678118654752f)));
                }
            }
        }
    }
}

// ---------------------------------------------------------------------------
// Flash attention with relative-position skew.
// score[q,k] = ( (q+rwb)·k[k]  +  [k<=q]*( q·re[j] + rb[j] ) ) * 0.25,
//   j = k - q + SQ - 1.  Full (non-causal) softmax over all 1024 keys.
// Block: 4 waves x 16 queries (QB=64). Per 32-key tile: AC (4 mfma),
// banded G = q·re^T over 48 cols (6 mfma), diagonal gather via __shfl,
// online softmax, P->LDS->A-frag, PV (4 mfma, V pre-transposed [dh][S]).
// ---------------------------------------------------------------------------
__global__ __launch_bounds__(256) void k_attn(
    const unsigned short* __restrict__ q, const unsigned short* __restrict__ k,
    const unsigned short* __restrict__ vt, const unsigned short* __restrict__ reb,
    const float* __restrict__ rb, const float* __restrict__ rwb,
    unsigned short* __restrict__ ao) {
    const int t = threadIdx.x, w = t >> 6, l = t & 63, g = l >> 4, c = l & 15;
    const int bh = blockIdx.x, b = bh >> 4, h = bh & 15;
    const int q_base = blockIdx.y * 64 + w * 16;

    __shared__ float rb_s[SQ];
    __shared__ unsigned short p_s[4][640];  // 16 rows x stride 40 per wave
    for (int i = t; i < SQ; i += 256) rb_s[i] = rb[h * MAXK + 640 + i];
    __syncthreads();

    const unsigned short* qp = q + ((long)bh * SQ + q_base) * DH;
    const unsigned short* kp = k + (long)bh * SQ * DH;
    const unsigned short* vp = vt + (long)bh * DH * SQ;
    const unsigned short* rp = reb + (long)h * SQ * DH;

    short8 qf[2], qrf[2];
#pragma unroll
    for (int kk = 0; kk < 2; kk++) {
        qf[kk] = *(const short8*)(qp + c * DH + kk * 32 + g * 8);
        short8 tmp;
#pragma unroll
        for (int e = 0; e < 8; e++) {
            float vq = bf2f((unsigned short)qf[kk][e]) + rwb[h * DH + kk * 32 + g * 8 + e];
            tmp[e] = (short)f2bf(vq);
        }
        qrf[kk] = tmp;
    }

    f32x4 O[4];
    float mrow[4], lrow[4];
#pragma unroll
    for (int r = 0; r < 4; r++) { mrow[r] = -1e30f; lrow[r] = 0.f; }
#pragma unroll
    for (int dt = 0; dt < 4; dt++) O[dt] = (f32x4){0.f, 0.f, 0.f, 0.f};

    for (int kt = 0; kt < SQ / 32; kt++) {
        const int k0 = kt * 32;
        // ---- AC = (q+rwb) . k^T  (two 16-col tiles) ----
        f32x4 ac[2];
#pragma unroll
        for (int tt = 0; tt < 2; tt++) {
            short8 kf0 = *(const short8*)(kp + (k0 + tt * 16 + c) * DH + g * 8);
            short8 kf1 = *(const short8*)(kp + (k0 + tt * 16 + c) * DH + 32 + g * 8);
            f32x4 zz = (f32x4){0.f, 0.f, 0.f, 0.f};
            zz = __builtin_amdgcn_mfma_f32_16x16x32_bf16(qrf[0], kf0, zz, 0, 0, 0);
            zz = __builtin_amdgcn_mfma_f32_16x16x32_bf16(qrf[1], kf1, zz, 0, 0, 0);
            ac[tt] = zz;
        }
        // ---- banded G = q . re^T over 48 cols, + rb folded in ----
        const int jb = k0 - q_base + SQ - 16;
        f32x4 G[3];
#pragma unroll
        for (int t2 = 0; t2 < 3; t2++) {
            int jr = jb + t2 * 16 + c;
            int jcl = jr < 0 ? 0 : (jr > SQ - 1 ? SQ - 1 : jr);
            short8 g0 = *(const short8*)(rp + (long)jcl * DH + g * 8);
            short8 g1 = *(const short8*)(rp + (long)jcl * DH + 32 + g * 8);
            f32x4 zz = (f32x4){0.f, 0.f, 0.f, 0.f};
            zz = __builtin_amdgcn_mfma_f32_16x16x32_bf16(qf[0], g0, zz, 0, 0, 0);
            zz = __builtin_amdgcn_mfma_f32_16x16x32_bf16(qf[1], g1, zz, 0, 0, 0);
            const float rbv = rb_s[jcl];
#pragma unroll
            for (int r = 0; r < 4; r++) zz[r] += rbv;
            G[t2] = zz;
        }
        // ---- diagonal gather + score assembly ----
        float sc[2][4];
#pragma unroll
        for (int tt = 0; tt < 2; tt++) {
#pragma unroll
            for (int r = 0; r < 4; r++) {
                const int qi = g * 4 + r;
                const int ki = tt * 16 + c;
                const int mm = ki - qi + 15;
                const int sl = (l & 48) | (mm & 15);
                const float glo = __shfl(G[tt][r], sl, 64);
                const float ghi = __shfl(G[tt + 1][r], sl, 64);
                const float gsel = ((mm >> 4) == tt) ? glo : ghi;
                const bool valid = (k0 + ki) <= (q_base + qi);
                sc[tt][r] = (ac[tt][r] + (valid ? gsel : 0.f)) * 0.25f;
            }
        }
        // ---- online softmax ----
        float corr[4];
#pragma unroll
        for (int r = 0; r < 4; r++) {
            float v = fmaxf(sc[0][r], sc[1][r]);
            v = fmaxf(v, __shfl_xor(v, 1)); v = fmaxf(v, __shfl_xor(v, 2));
            v = fmaxf(v, __shfl_xor(v, 4)); v = fmaxf(v, __shfl_xor(v, 8));
            const float mn = fmaxf(mrow[r], v);
            corr[r] = exp2f((mrow[r] - mn) * L2E);
            const float p0 = exp2f((sc[0][r] - mn) * L2E);
            const float p1 = exp2f((sc[1][r] - mn) * L2E);
            float ps = p0 + p1;
            ps += __shfl_xor(ps, 1); ps += __shfl_xor(ps, 2);
            ps += __shfl_xor(ps, 4); ps += __shfl_xor(ps, 8);
            lrow[r] = lrow[r] * corr[r] + ps;
            mrow[r] = mn;
            p_s[w][(g * 4 + r) * 40 + c] = f2bf(p0);
            p_s[w][(g * 4 + r) * 40 + 16 + c] = f2bf(p1);
        }
#pragma unroll
        for (int dt = 0; dt < 4; dt++)
#pragma unroll
            for (int r = 0; r < 4; r++) O[dt][r] *= corr[r];
        __syncthreads();  // cross-lane P visibility (all waves iterate uniformly)
        // ---- PV ----
        const short8 pf = *(const short8*)&p_s[w][c * 40 + g * 8];
#pragma unroll
        for (int dt = 0; dt < 4; dt++) {
            short8 vf = *(const short8*)(vp + (dt * 16 + c) * SQ + k0 + g * 8);
            O[dt] = __builtin_amdgcn_mfma_f32_16x16x32_bf16(pf, vf, O[dt], 0, 0, 0);
        }
    }

#pragma unroll
    for (int r = 0; r < 4; r++) {
        const float rl = 1.f / lrow[r];
        const int s = q_base + g * 4 + r;
#pragma unroll
        for (int dt = 0; dt < 4; dt++) {
            ao[((long)(b * SQ + s)) * DM + h * DH + dt * 16 + c] = f2bf(O[dt][r] * rl);
        }
    }
}

// ---------------------------------------------------------------------------
extern "C" void kernel_launch(void* const* d_in, const int* in_sizes, int n_in,
                              void* d_out, int out_size, void* d_ws, size_t ws_size,
                              hipStream_t stream) {
    const int* seq = (const int*)d_in[0];
    const float* emb = (const float*)d_in[4];
    const float* Wq = (const float*)d_in[5];
    const float* Wk = (const float*)d_in[6];
    const float* Wv = (const float*)d_in[7];
    const float* Wo = (const float*)d_in[8];
    const float* remb = (const float*)d_in[9];
    const float* rwb = (const float*)d_in[10];
    const float* rbias = (const float*)d_in[11];
    const float* ln1g = (const float*)d_in[12];
    const float* ln1b = (const float*)d_in[13];
    const float* ln2g = (const float*)d_in[14];
    const float* ln2b = (const float*)d_in[15];
    const float* w1 = (const float*)d_in[16];
    const float* b1 = (const float*)d_in[17];
    const float* w2 = (const float*)d_in[18];
    const float* b2 = (const float*)d_in[19];

    float* x = (float*)d_out;
    char* ws = (char*)d_ws;
    unsigned short* xb  = (unsigned short*)(ws);
    unsigned short* qb  = (unsigned short*)(ws + (8l  << 20));
    unsigned short* kb  = (unsigned short*)(ws + (16l << 20));
    unsigned short* vtb = (unsigned short*)(ws + (24l << 20));
    unsigned short* aob = (unsigned short*)(ws + (32l << 20));
    unsigned short* rebb = (unsigned short*)(ws + (40l << 20));
    unsigned short* hbb = (unsigned short*)(ws + (48l << 20));

    k_embed<<<dim3(ROWS), dim3(256), 0, stream>>>(seq, emb, x, xb);
    k_reb<<<dim3(4096), dim3(256), 0, stream>>>(remb, rebb);

    for (int i = 0; i < 4; i++) {
        const long wOff = (long)i * DM * DM;
        k_gemm<2, 0><<<dim3(8, 64, 3), dim3(256), 0, stream>>>(
            xb, Wq + wOff, Wk + wOff, Wv + wOff, DM, DM, nullptr, nullptr, qb, kb, vtb);
        k_attn<<<dim3(64, 16), dim3(256), 0, stream>>>(
            qb, kb, vtb, rebb + (long)i * NH * SQ * DH, rbias + (long)i * NH * MAXK,
            rwb + (long)i * NH * DH, aob);
        k_gemm<2, 1><<<dim3(8, 64, 1), dim3(256), 0, stream>>>(
            aob, Wo + wOff, nullptr, nullptr, DM, DM, x, nullptr, nullptr, nullptr, nullptr);
        k_ln<<<dim3(ROWS), dim3(256), 0, stream>>>(x, xb, ln1g + i * DM, ln1b + i * DM);
        k_gemm<4, 2><<<dim3(32, 32, 1), dim3(256), 0, stream>>>(
            xb, w1 + (long)i * FFD * DM, nullptr, nullptr, DM, FFD, nullptr,
            b1 + (long)i * FFD, hbb, nullptr, nullptr);
        k_gemm<2, 1><<<dim3(8, 64, 1), dim3(256), 0, stream>>>(
            hbb, w2 + (long)i * DM * FFD, nullptr, nullptr, FFD, DM, x,
            b2 + (long)i * DM, nullptr, nullptr, nullptr);
        k_ln<<<dim3(ROWS), dim3(256), 0, stream>>>(x, xb, ln2g + i * DM, ln2b + i * DM);
    }
}

// Round 2
// 2273.221 us; speedup vs baseline: 1.2169x; 1.2169x over previous
//
#include <hip/hip_runtime.h>
#include <stdint.h>

#define DM 1024
#define NH 16
#define DH 64
#define SQ 1024
#define NB 4
#define FFD 4096
#define MAXK 1664
#define ROWS 4096
#define L2E 1.4426950408889634f

typedef __attribute__((ext_vector_type(8))) short short8;
typedef __attribute__((ext_vector_type(4))) float f32x4;
typedef unsigned int u32;

static __device__ __forceinline__ unsigned short f2bf(float f) {
    unsigned u = __float_as_uint(f);
    return (unsigned short)((u + 0x7fffu + ((u >> 16) & 1u)) >> 16);
}
static __device__ __forceinline__ float bf2f(unsigned short s) {
    return __uint_as_float(((unsigned)s) << 16);
}
static __device__ __forceinline__ void gl16(const void* g, void* l) {
    __builtin_amdgcn_global_load_lds((const __attribute__((address_space(1))) u32*)g,
                                     (__attribute__((address_space(3))) u32*)l, 16, 0, 0);
}

// ---------------- embedding lookup: x fp32 (d_out) + xb bf16 ----------------
__global__ __launch_bounds__(256) void k_embed(const int* __restrict__ seq,
                                               const float* __restrict__ emb,
                                               float* __restrict__ x,
                                               unsigned short* __restrict__ xb) {
    const int row = blockIdx.x, t = threadIdx.x;
    const int tok = seq[row];
    const float4 v = *(const float4*)(emb + (long)tok * DM + t * 4);
    *(float4*)(x + (long)row * DM + t * 4) = v;
    ushort4 o; o.x = f2bf(v.x); o.y = f2bf(v.y); o.z = f2bf(v.z); o.w = f2bf(v.w);
    *(ushort4*)(xb + (long)row * DM + t * 4) = o;
}

// ------------- r_emb[:, :, -SQ:, :] -> bf16 [L][H][SQ][DH] ------------------
__global__ __launch_bounds__(256) void k_reb(const float* __restrict__ re,
                                             unsigned short* __restrict__ reb) {
    const long e = ((long)blockIdx.x * 256 + threadIdx.x) * 4;
    const int d = (int)(e & 63);
    const long rem = e >> 6;
    const int j = (int)(rem & 1023);
    const long lh = rem >> 10;
    const float4 v = *(const float4*)(re + (lh * MAXK + 640 + j) * DH + d);
    ushort4 o; o.x = f2bf(v.x); o.y = f2bf(v.y); o.z = f2bf(v.z); o.w = f2bf(v.w);
    *(ushort4*)(reb + e) = o;
}

// ---------------- fp32 -> bf16 weight conversion ---------------------------
__global__ __launch_bounds__(256) void k_cvt(const float* __restrict__ s,
                                             unsigned short* __restrict__ d, int n) {
    const long i = ((long)blockIdx.x * 256 + threadIdx.x) * 8;
    if (i >= n) return;
    const float4 a = *(const float4*)(s + i);
    const float4 b = *(const float4*)(s + i + 4);
    ushort4 o0, o1;
    o0.x = f2bf(a.x); o0.y = f2bf(a.y); o0.z = f2bf(a.z); o0.w = f2bf(a.w);
    o1.x = f2bf(b.x); o1.y = f2bf(b.y); o1.z = f2bf(b.z); o1.w = f2bf(b.w);
    *(ushort4*)(d + i) = o0; *(ushort4*)(d + i + 4) = o1;
}
__global__ __launch_bounds__(256) void k_cvt3(const float* __restrict__ s0,
                                              const float* __restrict__ s1,
                                              const float* __restrict__ s2,
                                              unsigned short* __restrict__ d) {
    const float* s = (blockIdx.z == 0) ? s0 : ((blockIdx.z == 1) ? s1 : s2);
    const long i = ((long)blockIdx.x * 256 + threadIdx.x) * 8;
    const float4 a = *(const float4*)(s + i);
    const float4 b = *(const float4*)(s + i + 4);
    ushort4 o0, o1;
    o0.x = f2bf(a.x); o0.y = f2bf(a.y); o0.z = f2bf(a.z); o0.w = f2bf(a.w);
    o1.x = f2bf(b.x); o1.y = f2bf(b.y); o1.z = f2bf(b.z); o1.w = f2bf(b.w);
    unsigned short* dz = d + (long)blockIdx.z * (DM * DM);
    *(ushort4*)(dz + i) = o0; *(ushort4*)(dz + i + 4) = o1;
}

// -------- LayerNorm in place on x (fp32), also writes xb (bf16) -------------
__global__ __launch_bounds__(256) void k_ln(float* __restrict__ x,
                                            unsigned short* __restrict__ xb,
                                            const float* __restrict__ gw,
                                            const float* __restrict__ bw) {
    const int row = blockIdx.x, t = threadIdx.x;
    float4 v = *(const float4*)(x + (long)row * DM + t * 4);
    float s = v.x + v.y + v.z + v.w;
    float sq = v.x * v.x + v.y * v.y + v.z * v.z + v.w * v.w;
#pragma unroll
    for (int mk = 1; mk < 64; mk <<= 1) { s += __shfl_xor(s, mk); sq += __shfl_xor(sq, mk); }
    __shared__ float red[8];
    if ((t & 63) == 0) { red[(t >> 6) * 2] = s; red[(t >> 6) * 2 + 1] = sq; }
    __syncthreads();
    const float ts = red[0] + red[2] + red[4] + red[6];
    const float tq = red[1] + red[3] + red[5] + red[7];
    const float mu = ts * (1.f / DM);
    const float rstd = rsqrtf(tq * (1.f / DM) - mu * mu + 1e-5f);
    const float4 g4 = *(const float4*)(gw + t * 4);
    const float4 b4 = *(const float4*)(bw + t * 4);
    float4 o;
    o.x = (v.x - mu) * rstd * g4.x + b4.x;
    o.y = (v.y - mu) * rstd * g4.y + b4.y;
    o.z = (v.z - mu) * rstd * g4.z + b4.z;
    o.w = (v.w - mu) * rstd * g4.w + b4.w;
    *(float4*)(x + (long)row * DM + t * 4) = o;
    ushort4 ob; ob.x = f2bf(o.x); ob.y = f2bf(o.y); ob.z = f2bf(o.z); ob.w = f2bf(o.w);
    *(ushort4*)(xb + (long)row * DM + t * 4) = ob;
}

// ---------------------------------------------------------------------------
// GEMM (m97 structure): C[M,N] = A(bf16,[M,K] rm) * B(bf16,[N,K] rm)^T
// 128x128 tile, BK=32, 4 waves (2x2), 4x4 16x16x32 MFMA frags per wave.
// Both operands staged via global_load_lds width=16, linear LDS [128][32].
// EPI 0: z selects {q,k,v} dest; q/k -> [B,H,S,dh] bf16, v -> [B,H,dh,S] bf16
// EPI 1: xres[m*DM+n] += acc + bias   (fp32 residual accumulate)
// EPI 2: d0[m*N+n] = bf16(gelu(acc + bias))
// ---------------------------------------------------------------------------
template <int EPI>
__global__ __launch_bounds__(256) void k_gemm(
    const unsigned short* __restrict__ A, const unsigned short* __restrict__ B,
    const int K, const int N,
    float* __restrict__ xres, const float* __restrict__ bias,
    unsigned short* __restrict__ d0, unsigned short* __restrict__ d1,
    unsigned short* __restrict__ d2) {
    __shared__ unsigned short As[128 * 32];
    __shared__ unsigned short Bs[128 * 32];
    const int t = threadIdx.x;
    const int w = t >> 6, l = t & 63, g = l >> 4, c = l & 15;
    const int z = blockIdx.z;
    const unsigned short* Bw = B + (long)z * ((long)N * K);
    const long m0 = (long)blockIdx.y * 128, n0 = (long)blockIdx.x * 128;
    // staging: wave w covers chunks (2w, 2w+1); chunk = 16 rows; lane l -> row l/4, seg (l&3)*8
    const int lrow = l >> 2, lseg = (l & 3) << 3;
    const unsigned short* ag0 = A + (m0 + (w * 2 + 0) * 16 + lrow) * (long)K + lseg;
    const unsigned short* ag1 = A + (m0 + (w * 2 + 1) * 16 + lrow) * (long)K + lseg;
    const unsigned short* bg0 = Bw + (n0 + (w * 2 + 0) * 16 + lrow) * (long)K + lseg;
    const unsigned short* bg1 = Bw + (n0 + (w * 2 + 1) * 16 + lrow) * (long)K + lseg;
    unsigned short* al0 = &As[(w * 2 + 0) * 512];
    unsigned short* al1 = &As[(w * 2 + 1) * 512];
    unsigned short* bl0 = &Bs[(w * 2 + 0) * 512];
    unsigned short* bl1 = &Bs[(w * 2 + 1) * 512];

    f32x4 acc[4][4];
#pragma unroll
    for (int i = 0; i < 4; i++)
#pragma unroll
        for (int j = 0; j < 4; j++) acc[i][j] = (f32x4){0.f, 0.f, 0.f, 0.f};
    const int wr = (w >> 1) * 64, wc = (w & 1) * 64;

    for (int kt = 0; kt < K; kt += 32) {
        gl16(ag0 + kt, al0);
        gl16(ag1 + kt, al1);
        gl16(bg0 + kt, bl0);
        gl16(bg1 + kt, bl1);
        __syncthreads();
        short8 aF[4], bF[4];
#pragma unroll
        for (int i = 0; i < 4; i++) aF[i] = *(const short8*)&As[(wr + i * 16 + c) * 32 + g * 8];
#pragma unroll
        for (int j = 0; j < 4; j++) bF[j] = *(const short8*)&Bs[(wc + j * 16 + c) * 32 + g * 8];
#pragma unroll
        for (int i = 0; i < 4; i++)
#pragma unroll
            for (int j = 0; j < 4; j++)
                acc[i][j] = __builtin_amdgcn_mfma_f32_16x16x32_bf16(aF[i], bF[j], acc[i][j], 0, 0, 0);
        __syncthreads();
    }

#pragma unroll
    for (int i = 0; i < 4; i++) {
#pragma unroll
        for (int j = 0; j < 4; j++) {
            const long ncol = n0 + wc + j * 16 + c;
            float bval = 0.f;
            if (EPI != 0) bval = (bias != nullptr) ? bias[ncol] : 0.f;
#pragma unroll
            for (int r = 0; r < 4; r++) {
                const long mrow = m0 + wr + i * 16 + g * 4 + r;
                const float vv = acc[i][j][r];
                if (EPI == 0) {
                    const long bb = mrow >> 10, ss = mrow & 1023, hh = ncol >> 6, dd = ncol & 63;
                    if (z == 0)      d0[((bb * NH + hh) * SQ + ss) * DH + dd] = f2bf(vv);
                    else if (z == 1) d1[((bb * NH + hh) * SQ + ss) * DH + dd] = f2bf(vv);
                    else             d2[((bb * NH + hh) * DH + dd) * SQ + ss] = f2bf(vv);
                } else if (EPI == 1) {
                    xres[mrow * DM + ncol] += vv + bval;
                } else {
                    const float xg = vv + bval;
                    d0[mrow * (long)N + ncol] = f2bf(0.5f * xg * (1.f + erff(xg * 0.70710678118654752f)));
                }
            }
        }
    }
}

// ---------------------------------------------------------------------------
// Flash attention with relative-position skew, 64-key tiles.
// score[q,k] = ( (q+rwb)·k[k]  +  [k<=q]*( q·re[j] + rb[j] ) ) * 0.25,
//   j = k - q + SQ - 1.  Full softmax over all 1024 keys.
// 4 waves x 16 queries. Per 64-key tile: AC (8 mfma), banded G over 80 cols
// (10 mfma), diagonal gather via __shfl, one online-softmax update,
// P->wave-private LDS->A-frag (no barrier), PV (8 mfma, V^T [dh][S]).
// ---------------------------------------------------------------------------
__global__ __launch_bounds__(256) void k_attn(
    const unsigned short* __restrict__ q, const unsigned short* __restrict__ k,
    const unsigned short* __restrict__ vt, const unsigned short* __restrict__ reb,
    const float* __restrict__ rb, const float* __restrict__ rwb,
    unsigned short* __restrict__ ao) {
    const int t = threadIdx.x, w = t >> 6, l = t & 63, g = l >> 4, c = l & 15;
    const int bh = blockIdx.x, b = bh >> 4, h = bh & 15;
    const int q_base = blockIdx.y * 64 + w * 16;

    __shared__ float rb_s[SQ];
    __shared__ unsigned short p_s[4][16 * 72];  // wave-private, stride 72
    for (int i = t; i < SQ; i += 256) rb_s[i] = rb[h * MAXK + 640 + i];
    __syncthreads();

    const unsigned short* qp = q + ((long)bh * SQ + q_base) * DH;
    const unsigned short* kp = k + (long)bh * SQ * DH;
    const unsigned short* vp = vt + (long)bh * DH * SQ;
    const unsigned short* rp = reb + (long)h * SQ * DH;

    short8 qf[2], qrf[2];
#pragma unroll
    for (int kk = 0; kk < 2; kk++) {
        qf[kk] = *(const short8*)(qp + c * DH + kk * 32 + g * 8);
        short8 tmp;
#pragma unroll
        for (int e = 0; e < 8; e++) {
            float vq = bf2f((unsigned short)qf[kk][e]) + rwb[h * DH + kk * 32 + g * 8 + e];
            tmp[e] = (short)f2bf(vq);
        }
        qrf[kk] = tmp;
    }

    f32x4 O[4];
    float mrow[4], lrow[4];
#pragma unroll
    for (int r = 0; r < 4; r++) { mrow[r] = -1e30f; lrow[r] = 0.f; }
#pragma unroll
    for (int dt = 0; dt < 4; dt++) O[dt] = (f32x4){0.f, 0.f, 0.f, 0.f};

    for (int kt = 0; kt < SQ / 64; kt++) {
        const int k0 = kt * 64;
        // ---- AC = (q+rwb) . k^T  (four 16-col tiles) ----
        f32x4 ac[4];
#pragma unroll
        for (int tt = 0; tt < 4; tt++) {
            short8 kf0 = *(const short8*)(kp + (k0 + tt * 16 + c) * DH + g * 8);
            short8 kf1 = *(const short8*)(kp + (k0 + tt * 16 + c) * DH + 32 + g * 8);
            f32x4 zz = (f32x4){0.f, 0.f, 0.f, 0.f};
            zz = __builtin_amdgcn_mfma_f32_16x16x32_bf16(qrf[0], kf0, zz, 0, 0, 0);
            zz = __builtin_amdgcn_mfma_f32_16x16x32_bf16(qrf[1], kf1, zz, 0, 0, 0);
            ac[tt] = zz;
        }
        // ---- banded G = q . re^T over 80 cols, + rb folded in ----
        const int jb = k0 - q_base + SQ - 16;
        f32x4 G[5];
#pragma unroll
        for (int t2 = 0; t2 < 5; t2++) {
            int jr = jb + t2 * 16 + c;
            int jcl = jr < 0 ? 0 : (jr > SQ - 1 ? SQ - 1 : jr);
            short8 g0 = *(const short8*)(rp + (long)jcl * DH + g * 8);
            short8 g1 = *(const short8*)(rp + (long)jcl * DH + 32 + g * 8);
            f32x4 zz = (f32x4){0.f, 0.f, 0.f, 0.f};
            zz = __builtin_amdgcn_mfma_f32_16x16x32_bf16(qf[0], g0, zz, 0, 0, 0);
            zz = __builtin_amdgcn_mfma_f32_16x16x32_bf16(qf[1], g1, zz, 0, 0, 0);
            const float rbv = rb_s[jcl];
#pragma unroll
            for (int r = 0; r < 4; r++) zz[r] += rbv;
            G[t2] = zz;
        }
        // ---- diagonal gather + score assembly ----
        float sc[4][4];
#pragma unroll
        for (int tt = 0; tt < 4; tt++) {
#pragma unroll
            for (int r = 0; r < 4; r++) {
                const int qi = g * 4 + r;
                const int ki = tt * 16 + c;
                const int mm = ki - qi + 15;
                const int sl = (l & 48) | (mm & 15);
                const float glo = __shfl(G[tt][r], sl, 64);
                const float ghi = __shfl(G[tt + 1 < 5 ? tt + 1 : 4][r], sl, 64);
                const float gsel = ((mm >> 4) == tt) ? glo : ghi;
                const bool valid = (k0 + ki) <= (q_base + qi);
                sc[tt][r] = (ac[tt][r] + (valid ? gsel : 0.f)) * 0.25f;
            }
        }
        // ---- online softmax (one update per 64 keys) ----
        float corr[4];
#pragma unroll
        for (int r = 0; r < 4; r++) {
            float v = fmaxf(fmaxf(sc[0][r], sc[1][r]), fmaxf(sc[2][r], sc[3][r]));
            v = fmaxf(v, __shfl_xor(v, 1)); v = fmaxf(v, __shfl_xor(v, 2));
            v = fmaxf(v, __shfl_xor(v, 4)); v = fmaxf(v, __shfl_xor(v, 8));
            const float mn = fmaxf(mrow[r], v);
            corr[r] = exp2f((mrow[r] - mn) * L2E);
            float p0 = exp2f((sc[0][r] - mn) * L2E);
            float p1 = exp2f((sc[1][r] - mn) * L2E);
            float p2 = exp2f((sc[2][r] - mn) * L2E);
            float p3 = exp2f((sc[3][r] - mn) * L2E);
            float ps = (p0 + p1) + (p2 + p3);
            ps += __shfl_xor(ps, 1); ps += __shfl_xor(ps, 2);
            ps += __shfl_xor(ps, 4); ps += __shfl_xor(ps, 8);
            lrow[r] = lrow[r] * corr[r] + ps;
            mrow[r] = mn;
            const int prow = (g * 4 + r) * 72;
            p_s[w][prow + c] = f2bf(p0);
            p_s[w][prow + 16 + c] = f2bf(p1);
            p_s[w][prow + 32 + c] = f2bf(p2);
            p_s[w][prow + 48 + c] = f2bf(p3);
        }
#pragma unroll
        for (int dt = 0; dt < 4; dt++)
#pragma unroll
            for (int r = 0; r < 4; r++) O[dt][r] *= corr[r];
        // no barrier: p_s is wave-private; compiler inserts lgkmcnt waits
        const short8 pf0 = *(const short8*)&p_s[w][c * 72 + g * 8];
        const short8 pf1 = *(const short8*)&p_s[w][c * 72 + 32 + g * 8];
#pragma unroll
        for (int dt = 0; dt < 4; dt++) {
            short8 vf0 = *(const short8*)(vp + (dt * 16 + c) * SQ + k0 + g * 8);
            short8 vf1 = *(const short8*)(vp + (dt * 16 + c) * SQ + k0 + 32 + g * 8);
            O[dt] = __builtin_amdgcn_mfma_f32_16x16x32_bf16(pf0, vf0, O[dt], 0, 0, 0);
            O[dt] = __builtin_amdgcn_mfma_f32_16x16x32_bf16(pf1, vf1, O[dt], 0, 0, 0);
        }
    }

#pragma unroll
    for (int r = 0; r < 4; r++) {
        const float rl = 1.f / lrow[r];
        const int s = q_base + g * 4 + r;
#pragma unroll
        for (int dt = 0; dt < 4; dt++) {
            ao[((long)(b * SQ + s)) * DM + h * DH + dt * 16 + c] = f2bf(O[dt][r] * rl);
        }
    }
}

// ---------------------------------------------------------------------------
extern "C" void kernel_launch(void* const* d_in, const int* in_sizes, int n_in,
                              void* d_out, int out_size, void* d_ws, size_t ws_size,
                              hipStream_t stream) {
    const int* seq = (const int*)d_in[0];
    const float* emb = (const float*)d_in[4];
    const float* Wq = (const float*)d_in[5];
    const float* Wk = (const float*)d_in[6];
    const float* Wv = (const float*)d_in[7];
    const float* Wo = (const float*)d_in[8];
    const float* remb = (const float*)d_in[9];
    const float* rwb = (const float*)d_in[10];
    const float* rbias = (const float*)d_in[11];
    const float* ln1g = (const float*)d_in[12];
    const float* ln1b = (const float*)d_in[13];
    const float* ln2g = (const float*)d_in[14];
    const float* ln2b = (const float*)d_in[15];
    const float* w1 = (const float*)d_in[16];
    const float* b1 = (const float*)d_in[17];
    const float* w2 = (const float*)d_in[18];
    const float* b2 = (const float*)d_in[19];

    float* x = (float*)d_out;
    char* ws = (char*)d_ws;
    unsigned short* xb   = (unsigned short*)(ws);              // [0,8) MB
    unsigned short* qb   = (unsigned short*)(ws + (8l << 20)); // [8,16)
    unsigned short* kb   = (unsigned short*)(ws + (16l << 20)); // [16,24)
    unsigned short* vtb  = (unsigned short*)(ws + (24l << 20)); // [24,32)
    unsigned short* aob  = (unsigned short*)(ws + (32l << 20)); // [32,40)
    unsigned short* rebb = (unsigned short*)(ws + (40l << 20)); // [40,48)
    unsigned short* hbb  = (unsigned short*)(ws + (48l << 20)); // [48,80)
    // transient weight regions (reuse of dead buffers within a layer):
    unsigned short* wqkv = aob;  // 6 MB, consumed by QKV GEMM before attn writes aob
    unsigned short* wo_b = qb;   // 2 MB, after attn has consumed qb
    unsigned short* w1_b = kb;   // 8 MB, after attn has consumed kb
    unsigned short* w2_b = vtb;  // 8 MB, after attn has consumed vtb

    k_embed<<<dim3(ROWS), dim3(256), 0, stream>>>(seq, emb, x, xb);
    k_reb<<<dim3(4096), dim3(256), 0, stream>>>(remb, rebb);

    for (int i = 0; i < 4; i++) {
        const long wOff = (long)i * DM * DM;
        k_cvt3<<<dim3(512, 1, 3), dim3(256), 0, stream>>>(Wq + wOff, Wk + wOff, Wv + wOff, wqkv);
        k_gemm<0><<<dim3(8, 32, 3), dim3(256), 0, stream>>>(
            xb, wqkv, DM, DM, nullptr, nullptr, qb, kb, vtb);
        k_attn<<<dim3(64, 16), dim3(256), 0, stream>>>(
            qb, kb, vtb, rebb + (long)i * NH * SQ * DH, rbias + (long)i * NH * MAXK,
            rwb + (long)i * NH * DH, aob);
        k_cvt<<<dim3(512), dim3(256), 0, stream>>>(Wo + wOff, wo_b, DM * DM);
        k_gemm<1><<<dim3(8, 32, 1), dim3(256), 0, stream>>>(
            aob, wo_b, DM, DM, x, nullptr, nullptr, nullptr, nullptr);
        k_ln<<<dim3(ROWS), dim3(256), 0, stream>>>(x, xb, ln1g + i * DM, ln1b + i * DM);
        k_cvt<<<dim3(2048), dim3(256), 0, stream>>>(w1 + (long)i * FFD * DM, w1_b, FFD * DM);
        k_gemm<2><<<dim3(32, 32, 1), dim3(256), 0, stream>>>(
            xb, w1_b, DM, FFD, nullptr, b1 + (long)i * FFD, hbb, nullptr, nullptr);
        k_cvt<<<dim3(2048), dim3(256), 0, stream>>>(w2 + (long)i * DM * FFD, w2_b, DM * FFD);
        k_gemm<1><<<dim3(8, 32, 1), dim3(256), 0, stream>>>(
            hbb, w2_b, FFD, DM, x, b2 + (long)i * DM, nullptr, nullptr, nullptr);
        k_ln<<<dim3(ROWS), dim3(256), 0, stream>>>(x, xb, ln2g + i * DM, ln2b + i * DM);
    }
}